// Round 18
// baseline (1664.852 us; speedup 1.0000x reference)
//
#include <hip/hip_runtime.h>
#include <math.h>

// ---------------------------------------------------------------------------
// DeepBilateralNetCurves (HDRNet) forward, f32.
// B=2, lowres 3x256x256, fullres 3x1024x1024, grid 12x8x16x16, 16-pt curve.
//
// Round 17 post-mortem: all kernels < 40us; cost = exec (~55) + 5 gaps (~45).
// pred_k still recomputes fc1/fc2 per 512 blocks (24 of its 36 serial dots).
// Round 18 (5 launches):
//   splat (unchanged), gl01 {gconv0-wave || lconv0+lconv1 halo-fused},
//   fcall {gconv1 + fc0 + fc1 + fc2 per batch, pad-65 LDS, unrolled dots},
//   predp {act + 12 dots/wave}, apply (unchanged).
// ---------------------------------------------------------------------------

static inline int cdiv(int a, int b) { return (a + b - 1) / b; }

// ---- fused splat chain: img -> x3 (HWC), one block per 2x2 x3 tile ---------
__global__ __launch_bounds__(1024) void splat_k(
    const float* __restrict__ img,
    const float* __restrict__ w0, const float* __restrict__ b0,
    const float* __restrict__ w1, const float* __restrict__ b1,
    const float* __restrict__ w2, const float* __restrict__ b2,
    const float* __restrict__ w3, const float* __restrict__ b3,
    float* __restrict__ x3out, int B) {
    __shared__ float simg[3 * 47 * 48];  // img tile, 26.4 KB (48-col stride)
    __shared__ float s0[23 * 23 * 8];    // x0 halo tile, 16.9 KB
    __shared__ float s1[11 * 11 * 16];   // x1 halo tile, 7.7 KB
    __shared__ float s2[5 * 5 * 32];     // x2 tile, 3.2 KB

    const int t  = threadIdx.x;
    const int b  = blockIdx.x >> 6;
    const int ty = (blockIdx.x >> 3) & 7;
    const int tx = blockIdx.x & 7;
    const int y0base = 16 * ty - 7, x0base = 16 * tx - 7;
    const int y1base = 8 * ty - 3,  x1base = 8 * tx - 3;
    const int y2base = 4 * ty - 1,  x2base = 4 * tx - 1;
    const int imgY0 = 32 * ty - 15, imgX0 = 32 * tx - 15;
    const float* ib = img + (size_t)b * 3 * 65536;

    for (int i = t; i < 3 * 47 * 47; i += 1024) {
        int xx = i % 47;
        int yy = (i / 47) % 47;
        int c  = i / (47 * 47);
        int y = imgY0 + yy, x = imgX0 + xx;
        float v = 0.0f;
        if (y >= 0 && y < 256 && x >= 0 && x < 256)
            v = ib[c * 65536 + y * 256 + x];
        simg[(c * 47 + yy) * 48 + xx] = v;
    }
    __syncthreads();

    for (int i = t; i < 23 * 23 * 8; i += 1024) {
        int c  = i & 7;
        int xx = (i >> 3) % 23;
        int yy = (i >> 3) / 23;
        int y = y0base + yy, x = x0base + xx;
        float acc = 0.0f;
        if (y >= 0 && y < 128 && x >= 0 && x < 128) {
            acc = b0[c];
            const float* wr = w0 + c * 27;
#pragma unroll
            for (int ci = 0; ci < 3; ++ci)
#pragma unroll
                for (int ky = 0; ky < 3; ++ky)
#pragma unroll
                    for (int kx = 0; kx < 3; ++kx)
                        acc += simg[(ci * 47 + 2 * yy + ky) * 48 + 2 * xx + kx]
                             * wr[ci * 9 + ky * 3 + kx];
            acc = fmaxf(acc, 0.0f);
        }
        s0[i] = acc;
    }
    __syncthreads();

    for (int i = t; i < 11 * 11 * 16; i += 1024) {
        int c  = i & 15;
        int xx = (i >> 4) % 11;
        int yy = (i >> 4) / 11;
        int y = y1base + yy, x = x1base + xx;
        float acc = 0.0f;
        if (y >= 0 && y < 64 && x >= 0 && x < 64) {
            acc = b1[c];
            const float* wr = w1 + c * 72;
            int l0y = 2 * yy;
            int l0x = 2 * xx;
            for (int ci = 0; ci < 8; ++ci)
#pragma unroll
                for (int ky = 0; ky < 3; ++ky)
#pragma unroll
                    for (int kx = 0; kx < 3; ++kx)
                        acc += s0[((l0y + ky) * 23 + (l0x + kx)) * 8 + ci] * wr[ci * 9 + ky * 3 + kx];
            acc = fmaxf(acc, 0.0f);
        }
        s1[i] = acc;
    }
    __syncthreads();

    if (t < 5 * 5 * 32) {
        int i = t;
        int c  = i & 31;
        int xx = (i >> 5) % 5;
        int yy = (i >> 5) / 5;
        int y = y2base + yy, x = x2base + xx;
        float acc = 0.0f;
        if (y >= 0 && y < 32 && x >= 0 && x < 32) {
            acc = b2[c];
            const float* wr = w2 + c * 144;
            int l1y = 2 * yy;
            int l1x = 2 * xx;
            for (int ci = 0; ci < 16; ++ci)
#pragma unroll
                for (int ky = 0; ky < 3; ++ky)
#pragma unroll
                    for (int kx = 0; kx < 3; ++kx)
                        acc += s1[((l1y + ky) * 11 + (l1x + kx)) * 16 + ci] * wr[ci * 9 + ky * 3 + kx];
            acc = fmaxf(acc, 0.0f);
        }
        s2[i] = acc;
    }
    __syncthreads();

    {
        int out  = t >> 2;
        int part = t & 3;
        int c  = out & 63;
        int xx = (out >> 6) & 1;
        int yy = out >> 7;
        int l2y = 2 * yy, l2x = 2 * xx;
        const float* wr = w3 + c * 288;
        float acc = 0.0f;
        for (int ci = part; ci < 32; ci += 4)
#pragma unroll
            for (int ky = 0; ky < 3; ++ky)
#pragma unroll
                for (int kx = 0; kx < 3; ++kx)
                    acc += s2[((l2y + ky) * 5 + (l2x + kx)) * 32 + ci] * wr[ci * 9 + ky * 3 + kx];
        acc += __shfl_xor(acc, 1);
        acc += __shfl_xor(acc, 2);
        if (part == 0) {
            int y = 2 * ty + yy, x = 2 * tx + xx;
            acc = fmaxf(acc + b3[c], 0.0f);
            x3out[((size_t)(b * 16 + y) * 16 + x) * 64 + c] = acc;
        }
    }
}

// ---- wave-per-output conv (HWC input, lane = ci) ---------------------------
__device__ __forceinline__ void wave_conv_one(
    const float* __restrict__ in, const float* __restrict__ wgt,
    const float* __restrict__ bias, float* __restrict__ out,
    int B, int Cin, int Hin, int Win, int Cout, int Hout, int Wout,
    int stride, int relu, int out_chw, int wid, int lane) {
    int copw = (Cin == 64) ? 1 : 2;
    int cow  = Cout / copw;
    int ci   = lane & (Cin - 1);
    int cw = wid % cow;
    int wo = (wid / cow) % Wout;
    int ho = (wid / (cow * Wout)) % Hout;
    int b  = wid / (cow * Wout * Hout);
    int co = cw * copw + ((copw == 2) ? (lane >> 5) : 0);
    int hb = ho * stride - 1, wb = wo * stride - 1;
    const float* wp = wgt + ((size_t)co * Cin + ci) * 9;
    float acc = 0.0f;
#pragma unroll
    for (int ky = 0; ky < 3; ++ky) {
        int hi = hb + ky;
        if (hi < 0 || hi >= Hin) continue;
#pragma unroll
        for (int kx = 0; kx < 3; ++kx) {
            int wi = wb + kx;
            if (wi < 0 || wi >= Win) continue;
            acc += in[((size_t)(b * Hin + hi) * Win + wi) * Cin + ci] * wp[ky * 3 + kx];
        }
    }
    for (int m = 1; m < Cin; m <<= 1) acc += __shfl_xor(acc, m);
    if (ci == 0) {
        if (bias) acc += bias[co];
        if (relu) acc = fmaxf(acc, 0.0f);
        if (out_chw) out[((size_t)(b * Cout + co) * Hout + ho) * Wout + wo] = acc;
        else         out[((size_t)(b * Hout + ho) * Wout + wo) * Cout + co] = acc;
    }
}

// ---- gl01_k: gconv0 (wave) || {lconv0 + lconv1 halo-fused} ------------------
// First B*256 blocks (16 waves each): gconv0 wave-conv -> g0.
// Next B*4 blocks: 8x8 loc1 tile; loc0 halo 10x10x64 in LDS, then lconv1.
__global__ __launch_bounds__(1024) void gl01_k(
    const float* __restrict__ x3,
    const float* __restrict__ gw0, const float* __restrict__ gb0, float* __restrict__ g0,
    const float* __restrict__ lw0, const float* __restrict__ lb0,
    const float* __restrict__ lw1, float* __restrict__ loc1, int B) {
    __shared__ float s_l0[10 * 10 * 64];   // 25.6 KB
    const int t = threadIdx.x, w = t >> 6, lane = t & 63;
    const int NG = B * 256;

    if ((int)blockIdx.x < NG) {
        int wid = blockIdx.x * 16 + w;      // wid < B*4096 always
        wave_conv_one(x3, gw0, gb0, g0, B, 64, 16, 16, 64, 8, 8, 2, 1, 0, wid, lane);
        return;
    }
    const int lblk = blockIdx.x - NG;
    const int b = lblk >> 2, tile = lblk & 3;
    const int ty0 = (tile >> 1) * 8, tx0 = (tile & 1) * 8;

    // stage 1: lconv0 over halo tile [ty0-1, ty0+8] x [tx0-1, tx0+8]
    for (int i = t; i < 6400; i += 1024) {
        int co = i & 63, pos = i >> 6;
        int xx = pos % 10, yy = pos / 10;
        int y = ty0 - 1 + yy, x = tx0 - 1 + xx;
        float acc = 0.0f;
        if (y >= 0 && y < 16 && x >= 0 && x < 16) {
            acc = lb0[co];
            const float* wr = lw0 + (size_t)co * 576;
#pragma unroll 4
            for (int ci = 0; ci < 64; ++ci) {
#pragma unroll
                for (int ky = 0; ky < 3; ++ky) {
                    int hi = y - 1 + ky;
                    if (hi < 0 || hi >= 16) continue;
#pragma unroll
                    for (int kx = 0; kx < 3; ++kx) {
                        int wi = x - 1 + kx;
                        if (wi < 0 || wi >= 16) continue;
                        acc += x3[((size_t)(b * 16 + hi) * 16 + wi) * 64 + ci] * wr[ci * 9 + ky * 3 + kx];
                    }
                }
            }
            acc = fmaxf(acc, 0.0f);
        }
        s_l0[pos * 64 + co] = acc;   // zero outside image == pad-0 for lconv1
    }
    __syncthreads();

    // stage 2: lconv1 (no bias, no relu) from LDS halo tile
    for (int i = t; i < 4096; i += 1024) {
        int co = i & 63, pos = i >> 6;
        int xx = pos & 7, yy = pos >> 3;
        float acc = 0.0f;
        const float* wr = lw1 + (size_t)co * 576;
#pragma unroll 4
        for (int ci = 0; ci < 64; ++ci) {
#pragma unroll
            for (int ky = 0; ky < 3; ++ky)
#pragma unroll
                for (int kx = 0; kx < 3; ++kx)
                    acc += s_l0[((yy + ky) * 10 + (xx + kx)) * 64 + ci] * wr[ci * 9 + ky * 3 + kx];
        }
        int y = ty0 + yy, x = tx0 + xx;
        loc1[((size_t)(b * 16 + y) * 16 + x) * 64 + co] = acc;
    }
}

// ---- fcall_k: gconv1 + fc0 + fc1 + fc2, one block per batch -----------------
// g0 staged with pad-65 stride (bank-safe); all dots compile-time unrolled;
// per-wave serial dots: fc0 16 + fc1 8 + fc2 4 (within the <=24 rule).
__global__ __launch_bounds__(1024) void fcall_k(
    const float* __restrict__ g0,
    const float* __restrict__ gw1, const float* __restrict__ gb1,
    const float* __restrict__ fw0, const float* __restrict__ fb0,
    const float* __restrict__ fw1, const float* __restrict__ fb1,
    const float* __restrict__ fw2, const float* __restrict__ fb2,
    float* __restrict__ f2out) {
    __shared__ float s_g0[64 * 65];    // 8x8 positions x 64ch, pad-65
    __shared__ float s_g1[1024];
    __shared__ float s_f0[256];
    __shared__ float s_f1[128];
    const int t = threadIdx.x, w = t >> 6, lane = t & 63;
    const int b = blockIdx.x;

    for (int i = t; i < 4096; i += 1024)
        s_g0[(i >> 6) * 65 + (i & 63)] = g0[(size_t)b * 4096 + i];
    __syncthreads();

    // gconv1: one output per thread; t = co*16 + ho*4 + wo (CHW-flatten order)
    {
        int co = t >> 4, ho = (t >> 2) & 3, wo = t & 3;
        float acc = gb1[co];
        const float* wr = gw1 + (size_t)co * 576;
#pragma unroll 4
        for (int ci = 0; ci < 64; ++ci) {
#pragma unroll
            for (int ky = 0; ky < 3; ++ky) {
                int hi = 2 * ho - 1 + ky;
                if (hi < 0 || hi >= 8) continue;
#pragma unroll
                for (int kx = 0; kx < 3; ++kx) {
                    int wi = 2 * wo - 1 + kx;
                    if (wi < 0 || wi >= 8) continue;
                    acc += s_g0[(hi * 8 + wi) * 65 + ci] * wr[ci * 9 + ky * 3 + kx];
                }
            }
        }
        s_g1[t] = fmaxf(acc, 0.0f);
    }
    __syncthreads();

    // fc0: 256 outputs, 16 dots/wave, 16 loads in flight
    for (int o = w; o < 256; o += 16) {
        const float* wp = fw0 + (size_t)o * 1024;
        float acc = 0.0f;
#pragma unroll
        for (int k = 0; k < 16; ++k) acc += s_g1[lane + k * 64] * wp[lane + k * 64];
        for (int m = 1; m < 64; m <<= 1) acc += __shfl_xor(acc, m);
        if (lane == 0) s_f0[o] = fmaxf(acc + fb0[o], 0.0f);
    }
    __syncthreads();
    // fc1: 128 outputs, 8 dots/wave
    for (int o = w; o < 128; o += 16) {
        const float* wp = fw1 + (size_t)o * 256;
        float acc = 0.0f;
#pragma unroll
        for (int j = 0; j < 4; ++j) acc += s_f0[lane + j * 64] * wp[lane + j * 64];
        for (int m = 1; m < 64; m <<= 1) acc += __shfl_xor(acc, m);
        if (lane == 0) s_f1[o] = fmaxf(acc + fb1[o], 0.0f);
    }
    __syncthreads();
    // fc2: 64 outputs, 4 dots/wave (no relu)
    for (int o = w; o < 64; o += 16) {
        const float* wp = fw2 + (size_t)o * 128;
        float acc = s_f1[lane] * wp[lane] + s_f1[lane + 64] * wp[lane + 64];
        for (int m = 1; m < 64; m <<= 1) acc += __shfl_xor(acc, m);
        if (lane == 0) f2out[b * 64 + o] = acc + fb2[o];
    }
}

// ---- predp_k: act + pred only (fc2 precomputed) -----------------------------
// one cell per block, 8 waves, 12 dots/wave; act per-lane from global.
__global__ __launch_bounds__(512) void predp_k(
    const float* __restrict__ f2g, const float* __restrict__ loc1,
    const float* __restrict__ pw, const float* __restrict__ pb,
    float* __restrict__ sco) {
    const int t = threadIdx.x, wl = t >> 6, lane = t & 63;
    const int b = blockIdx.x >> 8, cell = blockIdx.x & 255;
    float act = fmaxf(f2g[b * 64 + lane] + loc1[((size_t)(b * 256 + cell)) * 64 + lane], 0.0f);
    float* so = sco + (size_t)b * 24576 + (size_t)cell * 96;
    for (int c = wl; c < 96; c += 8) {
        float acc = pw[(size_t)c * 64 + lane] * act;
        for (int m = 1; m < 64; m <<= 1) acc += __shfl_xor(acc, m);
        if (lane == 0) so[c] = acc + pb[c];
    }
}

// ---- apply_k: guide + slice (y-prereduced LDS) + affine apply ---------------
#define RSTRIDE 196   // 2*96 + 4 pad (floats); row base stays 16B-aligned
__global__ __launch_bounds__(256, 4) void apply_k(
    const float* __restrict__ img, const float* __restrict__ sco,
    const float* __restrict__ ccm_w, const float* __restrict__ ccm_b,
    const float* __restrict__ shifts, const float* __restrict__ slopes,
    const float* __restrict__ proj_w, const float* __restrict__ proj_b,
    float* __restrict__ out) {
    __shared__ __align__(16) float s_sco[4 * 96];     // 2x2 cells x 96
    __shared__ __align__(16) float s_R[32 * RSTRIDE]; // per-row y-interp

    const int t   = threadIdx.x;
    const int b   = blockIdx.x >> 10;
    const int rem = blockIdx.x & 1023;
    const int ty  = rem >> 5;
    const int tx  = rem & 31;
    const int fy0 = (ty - 1) >> 1;
    const int fx0 = (tx - 1) >> 1;

    if (t < 96) {
        int cell = t / 24;          // dy*2+dx
        int i4 = t % 24;
        int dy = cell >> 1, dx = cell & 1;
        int gy = min(max(fy0 + dy, 0), 15);
        int gx = min(max(fx0 + dx, 0), 15);
        float4 v = ((const float4*)(sco + ((size_t)b * 256 + gy * 16 + gx) * 96))[i4];
        ((float4*)(s_sco + cell * 96))[i4] = v;
    }
    __syncthreads();

    for (int idx = t; idx < 1536; idx += 256) {
        int q = idx % 24;
        int rowdx = idx / 24;
        int row = rowdx >> 1, dx = rowdx & 1;
        float ys = ((float)(ty * 32 + row) + 0.5f) * 0.015625f - 0.5f;
        float wy1 = ys - (float)fy0;
        float wy0 = 1.0f - wy1;
        float4 a0 = ((const float4*)(s_sco + dx * 96))[q];         // dy=0
        float4 a1 = ((const float4*)(s_sco + (2 + dx) * 96))[q];   // dy=1
        float4 v = make_float4(wy0 * a0.x + wy1 * a1.x, wy0 * a0.y + wy1 * a1.y,
                               wy0 * a0.z + wy1 * a1.z, wy0 * a0.w + wy1 * a1.w);
        ((float4*)(s_R + row * RSTRIDE + dx * 96))[q] = v;
    }
    __syncthreads();

    const size_t plane = 1024 * 1024;
    const float* ibase = img + (size_t)b * 3 * plane;
    float* obase = out + (size_t)b * 3 * plane;

    const int row = t >> 3;
    const int xg  = (t & 7) * 4;
    const int y = ty * 32 + row;
    const int x0 = tx * 32 + xg;
    const size_t off = (size_t)y * 1024 + x0;

    float4 r4 = *(const float4*)(ibase + off);
    float4 g4 = *(const float4*)(ibase + plane + off);
    float4 b4 = *(const float4*)(ibase + 2 * plane + off);
    const float rj[4] = { r4.x, r4.y, r4.z, r4.w };
    const float gj[4] = { g4.x, g4.y, g4.z, g4.w };
    const float bj[4] = { b4.x, b4.y, b4.z, b4.w };

    const float* Rrow = s_R + row * RSTRIDE;
    float o_r[4], o_g[4], o_b[4];

#pragma unroll
    for (int j = 0; j < 4; ++j) {
        float r = rj[j], g = gj[j], bl = bj[j];

        float gd = proj_b[0];
#pragma unroll
        for (int c = 0; c < 3; ++c) {
            float v = ccm_b[c] + ccm_w[c * 3 + 0] * r + ccm_w[c * 3 + 1] * g + ccm_w[c * 3 + 2] * bl;
            float acc = 0.0f;
#pragma unroll
            for (int p = 0; p < 16; ++p)
                acc += slopes[c * 16 + p] * fmaxf(v - shifts[c * 16 + p], 0.0f);
            gd += proj_w[c] * acc;
        }
        gd = fminf(fmaxf(gd, 0.0f), 1.0f);

        float xs = ((float)(x0 + j) + 0.5f) * 0.015625f - 0.5f;
        float wx1 = xs - (float)fx0;
        float wx0 = 1.0f - wx1;
        float gz = gd * 8.0f - 0.5f;
        float fzf = floorf(gz);
        int fz = (int)fzf;
        float wz1 = gz - fzf;
        float wz0 = 1.0f - wz1;

        float ar = 0.0f, ag = 0.0f, ab = 0.0f;
#pragma unroll
        for (int dz = 0; dz < 2; ++dz) {
            int zi = min(max(fz + dz, 0), 7);
            float wz = dz ? wz1 : wz0;
#pragma unroll
            for (int dx = 0; dx < 2; ++dx) {
                float wt = wz * (dx ? wx1 : wx0);
                const float4* gp = (const float4*)(Rrow + dx * 96 + zi * 12);
                float4 a0 = gp[0], a1 = gp[1], a2 = gp[2];
                ar += wt * (a0.x * r + a0.y * g + a0.z * bl + a0.w);
                ag += wt * (a1.x * r + a1.y * g + a1.z * bl + a1.w);
                ab += wt * (a2.x * r + a2.y * g + a2.z * bl + a2.w);
            }
        }
        o_r[j] = fminf(fmaxf(ar, 0.0f), 1.0f);
        o_g[j] = fminf(fmaxf(ag, 0.0f), 1.0f);
        o_b[j] = fminf(fmaxf(ab, 0.0f), 1.0f);
    }

    *(float4*)(obase + off)             = make_float4(o_r[0], o_r[1], o_r[2], o_r[3]);
    *(float4*)(obase + plane + off)     = make_float4(o_g[0], o_g[1], o_g[2], o_g[3]);
    *(float4*)(obase + 2 * plane + off) = make_float4(o_b[0], o_b[1], o_b[2], o_b[3]);
}

// ---------------------------------------------------------------------------

extern "C" void kernel_launch(void* const* d_in, const int* in_sizes, int n_in,
                              void* d_out, int out_size, void* d_ws, size_t ws_size,
                              hipStream_t stream) {
    const float* img_lo = (const float*)d_in[0];
    const float* img_fr = (const float*)d_in[1];
    const float* sw0 = (const float*)d_in[2];  const float* sb0 = (const float*)d_in[3];
    const float* sw1 = (const float*)d_in[4];  const float* sb1 = (const float*)d_in[5];
    const float* sw2 = (const float*)d_in[6];  const float* sb2 = (const float*)d_in[7];
    const float* sw3 = (const float*)d_in[8];  const float* sb3 = (const float*)d_in[9];
    const float* gw0 = (const float*)d_in[10]; const float* gb0 = (const float*)d_in[11];
    const float* gw1 = (const float*)d_in[12]; const float* gb1 = (const float*)d_in[13];
    const float* fw0 = (const float*)d_in[14]; const float* fb0 = (const float*)d_in[15];
    const float* fw1 = (const float*)d_in[16]; const float* fb1 = (const float*)d_in[17];
    const float* fw2 = (const float*)d_in[18]; const float* fb2 = (const float*)d_in[19];
    const float* lw0 = (const float*)d_in[20]; const float* lb0 = (const float*)d_in[21];
    const float* lw1 = (const float*)d_in[22];
    const float* pw  = (const float*)d_in[23]; const float* pb  = (const float*)d_in[24];
    const float* ccm_w  = (const float*)d_in[25]; const float* ccm_b = (const float*)d_in[26];
    const float* shifts = (const float*)d_in[27];
    const float* slopes = (const float*)d_in[28];
    const float* proj_w = (const float*)d_in[29];
    const float* proj_b = (const float*)d_in[30];
    float* out = (float*)d_out;

    const int B = in_sizes[0] / (3 * 256 * 256);   // = 2

    // workspace carve (floats)
    float* ws = (float*)d_ws;
    float* x3   = ws;                                // B*16*16*64    HWC
    float* g0   = x3 + (size_t)B * 64 * 16 * 16;     // B*8*8*64      HWC
    float* f2   = g0 + (size_t)B * 64 * 8 * 8;       // B*64
    float* loc1 = f2 + (size_t)B * 64;               // B*16*16*64    HWC
    float* sco  = loc1 + (size_t)B * 64 * 16 * 16;   // B*256*96

    // 1: fused splat chain (conv0..conv3)
    splat_k<<<B * 64, 1024, 0, stream>>>(img_lo, sw0, sb0, sw1, sb1, sw2, sb2, sw3, sb3, x3, B);
    // 2: gconv0 (wave) || lconv0+lconv1 (halo-fused)
    gl01_k<<<B * 256 + B * 4, 1024, 0, stream>>>(x3, gw0, gb0, g0, lw0, lb0, lw1, loc1, B);
    // 3: gconv1 + fc0 + fc1 + fc2 (one block per batch)
    fcall_k<<<B, 1024, 0, stream>>>(g0, gw1, gb1, fw0, fb0, fw1, fb1, fw2, fb2, f2);
    // 4: act + pred -> sco (one cell per block, 8 waves, 12 dots/wave)
    predp_k<<<B * 256, 512, 0, stream>>>(f2, loc1, pw, pb, sco);
    // 5: guide + slice + apply (32x32-px tiles, y-prereduced LDS)
    apply_k<<<B * 1024, 256, 0, stream>>>(img_fr, sco, ccm_w, ccm_b, shifts, slopes,
                                          proj_w, proj_b, out);
}

// Round 19
// 109.457 us; speedup vs baseline: 15.2101x; 15.2101x over previous
//
#include <hip/hip_runtime.h>
#include <math.h>

// ---------------------------------------------------------------------------
// DeepBilateralNetCurves (HDRNet) forward, f32.
// B=2, lowres 3x256x256, fullres 3x1024x1024, grid 12x8x16x16, 16-pt curve.
//
// Round 18 post-mortem: halo-fused lconv had uncoalesced per-lane WEIGHT rows
// (2304B lane stride) at 8-block parallelism -> 1519us. lconv stays wide.
// Round 19: revert to round-17 (115.9us best); pred_k 512->1024 threads
// (serial dots/wave 36->18, same per-output reduction order).
// 6 launches: splat, gl0, gl1, fc0, pred, apply.
// ---------------------------------------------------------------------------

static inline int cdiv(int a, int b) { return (a + b - 1) / b; }

// ---- fused splat chain: img -> x3 (HWC), one block per 2x2 x3 tile ---------
__global__ __launch_bounds__(1024) void splat_k(
    const float* __restrict__ img,
    const float* __restrict__ w0, const float* __restrict__ b0,
    const float* __restrict__ w1, const float* __restrict__ b1,
    const float* __restrict__ w2, const float* __restrict__ b2,
    const float* __restrict__ w3, const float* __restrict__ b3,
    float* __restrict__ x3out, int B) {
    __shared__ float simg[3 * 47 * 48];  // img tile, 26.4 KB (48-col stride)
    __shared__ float s0[23 * 23 * 8];    // x0 halo tile, 16.9 KB
    __shared__ float s1[11 * 11 * 16];   // x1 halo tile, 7.7 KB
    __shared__ float s2[5 * 5 * 32];     // x2 tile, 3.2 KB

    const int t  = threadIdx.x;
    const int b  = blockIdx.x >> 6;
    const int ty = (blockIdx.x >> 3) & 7;
    const int tx = blockIdx.x & 7;
    const int y0base = 16 * ty - 7, x0base = 16 * tx - 7;
    const int y1base = 8 * ty - 3,  x1base = 8 * tx - 3;
    const int y2base = 4 * ty - 1,  x2base = 4 * tx - 1;
    const int imgY0 = 32 * ty - 15, imgX0 = 32 * tx - 15;
    const float* ib = img + (size_t)b * 3 * 65536;

    for (int i = t; i < 3 * 47 * 47; i += 1024) {
        int xx = i % 47;
        int yy = (i / 47) % 47;
        int c  = i / (47 * 47);
        int y = imgY0 + yy, x = imgX0 + xx;
        float v = 0.0f;
        if (y >= 0 && y < 256 && x >= 0 && x < 256)
            v = ib[c * 65536 + y * 256 + x];
        simg[(c * 47 + yy) * 48 + xx] = v;
    }
    __syncthreads();

    for (int i = t; i < 23 * 23 * 8; i += 1024) {
        int c  = i & 7;
        int xx = (i >> 3) % 23;
        int yy = (i >> 3) / 23;
        int y = y0base + yy, x = x0base + xx;
        float acc = 0.0f;
        if (y >= 0 && y < 128 && x >= 0 && x < 128) {
            acc = b0[c];
            const float* wr = w0 + c * 27;
#pragma unroll
            for (int ci = 0; ci < 3; ++ci)
#pragma unroll
                for (int ky = 0; ky < 3; ++ky)
#pragma unroll
                    for (int kx = 0; kx < 3; ++kx)
                        acc += simg[(ci * 47 + 2 * yy + ky) * 48 + 2 * xx + kx]
                             * wr[ci * 9 + ky * 3 + kx];
            acc = fmaxf(acc, 0.0f);
        }
        s0[i] = acc;
    }
    __syncthreads();

    for (int i = t; i < 11 * 11 * 16; i += 1024) {
        int c  = i & 15;
        int xx = (i >> 4) % 11;
        int yy = (i >> 4) / 11;
        int y = y1base + yy, x = x1base + xx;
        float acc = 0.0f;
        if (y >= 0 && y < 64 && x >= 0 && x < 64) {
            acc = b1[c];
            const float* wr = w1 + c * 72;
            int l0y = 2 * yy;
            int l0x = 2 * xx;
            for (int ci = 0; ci < 8; ++ci)
#pragma unroll
                for (int ky = 0; ky < 3; ++ky)
#pragma unroll
                    for (int kx = 0; kx < 3; ++kx)
                        acc += s0[((l0y + ky) * 23 + (l0x + kx)) * 8 + ci] * wr[ci * 9 + ky * 3 + kx];
            acc = fmaxf(acc, 0.0f);
        }
        s1[i] = acc;
    }
    __syncthreads();

    if (t < 5 * 5 * 32) {
        int i = t;
        int c  = i & 31;
        int xx = (i >> 5) % 5;
        int yy = (i >> 5) / 5;
        int y = y2base + yy, x = x2base + xx;
        float acc = 0.0f;
        if (y >= 0 && y < 32 && x >= 0 && x < 32) {
            acc = b2[c];
            const float* wr = w2 + c * 144;
            int l1y = 2 * yy;
            int l1x = 2 * xx;
            for (int ci = 0; ci < 16; ++ci)
#pragma unroll
                for (int ky = 0; ky < 3; ++ky)
#pragma unroll
                    for (int kx = 0; kx < 3; ++kx)
                        acc += s1[((l1y + ky) * 11 + (l1x + kx)) * 16 + ci] * wr[ci * 9 + ky * 3 + kx];
            acc = fmaxf(acc, 0.0f);
        }
        s2[i] = acc;
    }
    __syncthreads();

    {
        int out  = t >> 2;
        int part = t & 3;
        int c  = out & 63;
        int xx = (out >> 6) & 1;
        int yy = out >> 7;
        int l2y = 2 * yy, l2x = 2 * xx;
        const float* wr = w3 + c * 288;
        float acc = 0.0f;
        for (int ci = part; ci < 32; ci += 4)
#pragma unroll
            for (int ky = 0; ky < 3; ++ky)
#pragma unroll
                for (int kx = 0; kx < 3; ++kx)
                    acc += s2[((l2y + ky) * 5 + (l2x + kx)) * 32 + ci] * wr[ci * 9 + ky * 3 + kx];
        acc += __shfl_xor(acc, 1);
        acc += __shfl_xor(acc, 2);
        if (part == 0) {
            int y = 2 * ty + yy, x = 2 * tx + xx;
            acc = fmaxf(acc + b3[c], 0.0f);
            x3out[((size_t)(b * 16 + y) * 16 + x) * 64 + c] = acc;
        }
    }
}

// ---- wave-per-output conv (HWC input, lane = ci) ---------------------------

__device__ __forceinline__ void wave_conv_one(
    const float* __restrict__ in, const float* __restrict__ wgt,
    const float* __restrict__ bias, float* __restrict__ out,
    int B, int Cin, int Hin, int Win, int Cout, int Hout, int Wout,
    int stride, int relu, int out_chw, int wid, int lane) {
    int copw = (Cin == 64) ? 1 : 2;
    int cow  = Cout / copw;
    int ci   = lane & (Cin - 1);
    int cw = wid % cow;
    int wo = (wid / cow) % Wout;
    int ho = (wid / (cow * Wout)) % Hout;
    int b  = wid / (cow * Wout * Hout);
    int co = cw * copw + ((copw == 2) ? (lane >> 5) : 0);
    int hb = ho * stride - 1, wb = wo * stride - 1;
    const float* wp = wgt + ((size_t)co * Cin + ci) * 9;
    float acc = 0.0f;
#pragma unroll
    for (int ky = 0; ky < 3; ++ky) {
        int hi = hb + ky;
        if (hi < 0 || hi >= Hin) continue;
#pragma unroll
        for (int kx = 0; kx < 3; ++kx) {
            int wi = wb + kx;
            if (wi < 0 || wi >= Win) continue;
            acc += in[((size_t)(b * Hin + hi) * Win + wi) * Cin + ci] * wp[ky * 3 + kx];
        }
    }
    for (int m = 1; m < Cin; m <<= 1) acc += __shfl_xor(acc, m);
    if (ci == 0) {
        if (bias) acc += bias[co];
        if (relu) acc = fmaxf(acc, 0.0f);
        if (out_chw) out[((size_t)(b * Cout + co) * Hout + ho) * Wout + wo] = acc;
        else         out[((size_t)(b * Hout + ho) * Wout + wo) * Cout + co] = acc;
    }
}

// gconv0 (64ch 16->8, s2) || lconv0 (64ch 16x16, s1, relu)
__global__ void gl0_k(const float* __restrict__ x3,
                      const float* __restrict__ gw, const float* __restrict__ gb, float* __restrict__ g0,
                      const float* __restrict__ lw, const float* __restrict__ lb, float* __restrict__ loc0,
                      int B) {
    int tid = blockIdx.x * blockDim.x + threadIdx.x;
    int wid = tid >> 6, lane = threadIdx.x & 63;
    int ng = B * 64 * 8 * 8;
    int nl = B * 64 * 16 * 16;
    if (wid < ng)            wave_conv_one(x3, gw, gb, g0,  B, 64, 16, 16, 64, 8, 8,  2, 1, 0, wid, lane);
    else if (wid < ng + nl)  wave_conv_one(x3, lw, lb, loc0, B, 64, 16, 16, 64, 16, 16, 1, 1, 0, wid - ng, lane);
}

// gconv1 (64ch 8->4, s2, CHW out for FC flatten) || lconv1 (no relu)
__global__ void gl1_k(const float* __restrict__ g0, const float* __restrict__ loc0,
                      const float* __restrict__ gw, const float* __restrict__ gb, float* __restrict__ g1,
                      const float* __restrict__ lw, float* __restrict__ loc1, int B) {
    int tid = blockIdx.x * blockDim.x + threadIdx.x;
    int wid = tid >> 6, lane = threadIdx.x & 63;
    int ng = B * 64 * 4 * 4;
    int nl = B * 64 * 16 * 16;
    if (wid < ng)            wave_conv_one(g0, gw, gb, g1,   B, 64, 8, 8,  64, 4, 4,  2, 1, 1, wid, lane);
    else if (wid < ng + nl)  wave_conv_one(loc0, lw, nullptr, loc1, B, 64, 16, 16, 64, 16, 16, 1, 0, 0, wid - ng, lane);
}

// fc0: wave per (b,o), 1024-dot, relu. Compile-time trip count (16 loads
// in flight; same summation order as j=lane,+64 loop).
__global__ void fc0_k(const float* __restrict__ g1, const float* __restrict__ fw0,
                      const float* __restrict__ fb0, float* __restrict__ f0, int B) {
    int tid  = blockIdx.x * blockDim.x + threadIdx.x;
    int wid  = tid >> 6;
    int lane = threadIdx.x & 63;
    if (wid >= B * 256) return;
    int o = wid & 255, b = wid >> 8;
    const float* ip = g1 + (size_t)b * 1024;
    const float* wp = fw0 + (size_t)o * 1024;
    float acc = 0.0f;
#pragma unroll
    for (int k = 0; k < 16; ++k) acc += ip[lane + k * 64] * wp[lane + k * 64];
    for (int m = 1; m < 64; m <<= 1) acc += __shfl_xor(acc, m);
    if (lane == 0) f0[wid] = fmaxf(acc + fb0[o], 0.0f);
}

// ---- pred_k: one cell per block, 16 waves ----------------------------------
// fc1/fc2 redundant per block (weights L2-hot); serial dots/wave: fc1 8,
// fc2 4, pred 6 (was 36 at 8 waves). Same per-output reduction order.
__global__ __launch_bounds__(1024) void pred_k(
    const float* __restrict__ f0g,
    const float* __restrict__ fw1, const float* __restrict__ fb1,
    const float* __restrict__ fw2, const float* __restrict__ fb2,
    const float* __restrict__ loc1,
    const float* __restrict__ pw, const float* __restrict__ pb,
    float* __restrict__ sco) {
    __shared__ float s_f0[256];
    __shared__ float s_f1[128];
    __shared__ float s_f2[64];
    __shared__ float s_loc[64];

    const int t    = threadIdx.x;
    const int b    = blockIdx.x >> 8;
    const int cell = blockIdx.x & 255;
    const int wl   = t >> 6;            // 0..15
    const int lane = t & 63;

    if (t < 256) s_f0[t] = f0g[b * 256 + t];
    else if (t < 320) s_loc[t - 256] = loc1[((size_t)(b * 256 + cell)) * 64 + (t - 256)];
    __syncthreads();

    for (int o = wl; o < 128; o += 16) {
        const float* wp = fw1 + (size_t)o * 256;
        float acc = 0.0f;
#pragma unroll
        for (int j = 0; j < 4; ++j) acc += s_f0[lane + j * 64] * wp[lane + j * 64];
        for (int m = 1; m < 64; m <<= 1) acc += __shfl_xor(acc, m);
        if (lane == 0) s_f1[o] = fmaxf(acc + fb1[o], 0.0f);
    }
    __syncthreads();
    for (int o = wl; o < 64; o += 16) {
        const float* wp = fw2 + (size_t)o * 128;
        float acc = s_f1[lane] * wp[lane] + s_f1[lane + 64] * wp[lane + 64];
        for (int m = 1; m < 64; m <<= 1) acc += __shfl_xor(acc, m);
        if (lane == 0) s_f2[o] = acc + fb2[o];
    }
    __syncthreads();

    float act = fmaxf(s_f2[lane] + s_loc[lane], 0.0f);
    float* so = sco + (size_t)b * 24576 + (size_t)cell * 96;
    for (int c = wl; c < 96; c += 16) {
        float acc = pw[(size_t)c * 64 + lane] * act;
        for (int m = 1; m < 64; m <<= 1) acc += __shfl_xor(acc, m);
        if (lane == 0) so[c] = acc + pb[c];
    }
}

// ---- apply_k: guide + slice (y-prereduced LDS) + affine apply ---------------
#define RSTRIDE 196   // 2*96 + 4 pad (floats); row base stays 16B-aligned
__global__ __launch_bounds__(256, 4) void apply_k(
    const float* __restrict__ img, const float* __restrict__ sco,
    const float* __restrict__ ccm_w, const float* __restrict__ ccm_b,
    const float* __restrict__ shifts, const float* __restrict__ slopes,
    const float* __restrict__ proj_w, const float* __restrict__ proj_b,
    float* __restrict__ out) {
    __shared__ __align__(16) float s_sco[4 * 96];     // 2x2 cells x 96
    __shared__ __align__(16) float s_R[32 * RSTRIDE]; // per-row y-interp

    const int t   = threadIdx.x;
    const int b   = blockIdx.x >> 10;
    const int rem = blockIdx.x & 1023;
    const int ty  = rem >> 5;
    const int tx  = rem & 31;
    const int fy0 = (ty - 1) >> 1;
    const int fx0 = (tx - 1) >> 1;

    if (t < 96) {
        int cell = t / 24;          // dy*2+dx
        int i4 = t % 24;
        int dy = cell >> 1, dx = cell & 1;
        int gy = min(max(fy0 + dy, 0), 15);
        int gx = min(max(fx0 + dx, 0), 15);
        float4 v = ((const float4*)(sco + ((size_t)b * 256 + gy * 16 + gx) * 96))[i4];
        ((float4*)(s_sco + cell * 96))[i4] = v;
    }
    __syncthreads();

    for (int idx = t; idx < 1536; idx += 256) {
        int q = idx % 24;
        int rowdx = idx / 24;
        int row = rowdx >> 1, dx = rowdx & 1;
        float ys = ((float)(ty * 32 + row) + 0.5f) * 0.015625f - 0.5f;
        float wy1 = ys - (float)fy0;
        float wy0 = 1.0f - wy1;
        float4 a0 = ((const float4*)(s_sco + dx * 96))[q];         // dy=0
        float4 a1 = ((const float4*)(s_sco + (2 + dx) * 96))[q];   // dy=1
        float4 v = make_float4(wy0 * a0.x + wy1 * a1.x, wy0 * a0.y + wy1 * a1.y,
                               wy0 * a0.z + wy1 * a1.z, wy0 * a0.w + wy1 * a1.w);
        ((float4*)(s_R + row * RSTRIDE + dx * 96))[q] = v;
    }
    __syncthreads();

    const size_t plane = 1024 * 1024;
    const float* ibase = img + (size_t)b * 3 * plane;
    float* obase = out + (size_t)b * 3 * plane;

    const int row = t >> 3;
    const int xg  = (t & 7) * 4;
    const int y = ty * 32 + row;
    const int x0 = tx * 32 + xg;
    const size_t off = (size_t)y * 1024 + x0;

    float4 r4 = *(const float4*)(ibase + off);
    float4 g4 = *(const float4*)(ibase + plane + off);
    float4 b4 = *(const float4*)(ibase + 2 * plane + off);
    const float rj[4] = { r4.x, r4.y, r4.z, r4.w };
    const float gj[4] = { g4.x, g4.y, g4.z, g4.w };
    const float bj[4] = { b4.x, b4.y, b4.z, b4.w };

    const float* Rrow = s_R + row * RSTRIDE;
    float o_r[4], o_g[4], o_b[4];

#pragma unroll
    for (int j = 0; j < 4; ++j) {
        float r = rj[j], g = gj[j], bl = bj[j];

        float gd = proj_b[0];
#pragma unroll
        for (int c = 0; c < 3; ++c) {
            float v = ccm_b[c] + ccm_w[c * 3 + 0] * r + ccm_w[c * 3 + 1] * g + ccm_w[c * 3 + 2] * bl;
            float acc = 0.0f;
#pragma unroll
            for (int p = 0; p < 16; ++p)
                acc += slopes[c * 16 + p] * fmaxf(v - shifts[c * 16 + p], 0.0f);
            gd += proj_w[c] * acc;
        }
        gd = fminf(fmaxf(gd, 0.0f), 1.0f);

        float xs = ((float)(x0 + j) + 0.5f) * 0.015625f - 0.5f;
        float wx1 = xs - (float)fx0;
        float wx0 = 1.0f - wx1;
        float gz = gd * 8.0f - 0.5f;
        float fzf = floorf(gz);
        int fz = (int)fzf;
        float wz1 = gz - fzf;
        float wz0 = 1.0f - wz1;

        float ar = 0.0f, ag = 0.0f, ab = 0.0f;
#pragma unroll
        for (int dz = 0; dz < 2; ++dz) {
            int zi = min(max(fz + dz, 0), 7);
            float wz = dz ? wz1 : wz0;
#pragma unroll
            for (int dx = 0; dx < 2; ++dx) {
                float wt = wz * (dx ? wx1 : wx0);
                const float4* gp = (const float4*)(Rrow + dx * 96 + zi * 12);
                float4 a0 = gp[0], a1 = gp[1], a2 = gp[2];
                ar += wt * (a0.x * r + a0.y * g + a0.z * bl + a0.w);
                ag += wt * (a1.x * r + a1.y * g + a1.z * bl + a1.w);
                ab += wt * (a2.x * r + a2.y * g + a2.z * bl + a2.w);
            }
        }
        o_r[j] = fminf(fmaxf(ar, 0.0f), 1.0f);
        o_g[j] = fminf(fmaxf(ag, 0.0f), 1.0f);
        o_b[j] = fminf(fmaxf(ab, 0.0f), 1.0f);
    }

    *(float4*)(obase + off)             = make_float4(o_r[0], o_r[1], o_r[2], o_r[3]);
    *(float4*)(obase + plane + off)     = make_float4(o_g[0], o_g[1], o_g[2], o_g[3]);
    *(float4*)(obase + 2 * plane + off) = make_float4(o_b[0], o_b[1], o_b[2], o_b[3]);
}

// ---------------------------------------------------------------------------

extern "C" void kernel_launch(void* const* d_in, const int* in_sizes, int n_in,
                              void* d_out, int out_size, void* d_ws, size_t ws_size,
                              hipStream_t stream) {
    const float* img_lo = (const float*)d_in[0];
    const float* img_fr = (const float*)d_in[1];
    const float* sw0 = (const float*)d_in[2];  const float* sb0 = (const float*)d_in[3];
    const float* sw1 = (const float*)d_in[4];  const float* sb1 = (const float*)d_in[5];
    const float* sw2 = (const float*)d_in[6];  const float* sb2 = (const float*)d_in[7];
    const float* sw3 = (const float*)d_in[8];  const float* sb3 = (const float*)d_in[9];
    const float* gw0 = (const float*)d_in[10]; const float* gb0 = (const float*)d_in[11];
    const float* gw1 = (const float*)d_in[12]; const float* gb1 = (const float*)d_in[13];
    const float* fw0 = (const float*)d_in[14]; const float* fb0 = (const float*)d_in[15];
    const float* fw1 = (const float*)d_in[16]; const float* fb1 = (const float*)d_in[17];
    const float* fw2 = (const float*)d_in[18]; const float* fb2 = (const float*)d_in[19];
    const float* lw0 = (const float*)d_in[20]; const float* lb0 = (const float*)d_in[21];
    const float* lw1 = (const float*)d_in[22];
    const float* pw  = (const float*)d_in[23]; const float* pb  = (const float*)d_in[24];
    const float* ccm_w  = (const float*)d_in[25]; const float* ccm_b = (const float*)d_in[26];
    const float* shifts = (const float*)d_in[27];
    const float* slopes = (const float*)d_in[28];
    const float* proj_w = (const float*)d_in[29];
    const float* proj_b = (const float*)d_in[30];
    float* out = (float*)d_out;

    const int B = in_sizes[0] / (3 * 256 * 256);   // = 2

    // workspace carve (floats)
    float* ws = (float*)d_ws;
    float* x3   = ws;                                // B*16*16*64    HWC
    float* g0   = x3 + (size_t)B * 64 * 16 * 16;     // B*8*8*64      HWC
    float* g1   = g0 + (size_t)B * 64 * 8 * 8;       // B*64*4*4      CHW
    float* f0   = g1 + (size_t)B * 64 * 4 * 4;       // B*256
    float* loc0 = f0 + (size_t)B * 256;              // B*16*16*64    HWC
    float* loc1 = loc0 + (size_t)B * 64 * 16 * 16;   // B*16*16*64    HWC
    float* sco  = loc1 + (size_t)B * 64 * 16 * 16;   // B*256*96

    const int T = 256;

    // 1: fused splat chain (conv0..conv3)
    splat_k<<<B * 64, 1024, 0, stream>>>(img_lo, sw0, sb0, sw1, sb1, sw2, sb2, sw3, sb3, x3, B);
    // 2: gconv0 || lconv0
    {
        int nwaves = B * 64 * 8 * 8 + B * 64 * 16 * 16;
        gl0_k<<<cdiv(nwaves * 64, T), T, 0, stream>>>(x3, gw0, gb0, g0, lw0, lb0, loc0, B);
    }
    // 3: gconv1 || lconv1
    {
        int nwaves = B * 64 * 4 * 4 + B * 64 * 16 * 16;
        gl1_k<<<cdiv(nwaves * 64, T), T, 0, stream>>>(g0, loc0, gw1, gb1, g1, lw1, loc1, B);
    }
    // 4: fc0 (wide, wave per output, unrolled dot)
    fc0_k<<<cdiv(B * 256 * 64, T), T, 0, stream>>>(g1, fw0, fb0, f0, B);
    // 5: fc1+fc2+pred -> sco (one cell per block, 16 waves)
    pred_k<<<B * 256, 1024, 0, stream>>>(f0, fw1, fb1, fw2, fb2, loc1, pw, pb, sco);
    // 6: guide + slice + apply (32x32-px tiles, y-prereduced LDS)
    apply_k<<<B * 1024, 256, 0, stream>>>(img_fr, sco, ccm_w, ccm_b, shifts, slopes,
                                          proj_w, proj_b, out);
}